// Round 1
// baseline (161.651 us; speedup 1.0000x reference)
//
#include <hip/hip_runtime.h>
#include <cstdint>

// DST-II via FFT, one 1024-point transform per wave, 1 row per wave.
// Y_k = DCT-II(u)_{N-1-k}, u_n = (-1)^n x_n; Makhoul: v_p = x_{2p} (p<512),
// v_p = -x_{2047-2p} (p>=512); V = DFT_1024(v); C_j = Re[e^{-i pi j/2048} V_j];
// Y_k = C_{1023-k}.
//
// DFT_1024, n = l + 64*n2 (l = lane, n2 = slot):
//  phase 1: in-lane DIF-16 over n2 -> slot s holds m2 = brev4(s);
//           twiddle W1024^{l*m2} (computed inline, trans pipe).
//  DFT_64 over l, l = c + 4d (c = l&3):
//   -> two-pass 4KB wave-level LDS transpose (lane' = c + 4*m2 holds all d)
//   -> in-lane DIT-16 over d (bit-rev input via read order, natural m out)
//   -> twiddle W64^{c*m}
//   -> cross-lane DFT_4 over c: shfl_xor(2), shfl_xor(1), output e = brev2(c).
//  k = m2 + 16*m + 256*e; then DCT post-twiddle, store Y[1023-k].

static constexpr int BR4[16] = {0, 8, 4, 12, 2, 10, 6, 14,
                                1, 9, 5, 13, 3, 11, 7, 15};
// W16^o = e^{-2 pi i o/16}
static constexpr float W16C[8] = {1.0f, 0.9238795325f, 0.7071067812f,
                                  0.3826834324f, 0.0f, -0.3826834324f,
                                  -0.7071067812f, -0.9238795325f};
static constexpr float W16S[8] = {-0.0f, -0.3826834324f, -0.7071067812f,
                                  -0.9238795325f, -1.0f, -0.9238795325f,
                                  -0.7071067812f, -0.3826834324f};

__device__ __forceinline__ float sinr(float r) {   // sin(2*pi*r)
  return __builtin_amdgcn_sinf(r);
}
__device__ __forceinline__ float cosr(float r) {   // cos(2*pi*r), r in [0,1)
  float t = r + 0.25f;
  t -= (t >= 1.0f) ? 1.0f : 0.0f;
  return __builtin_amdgcn_sinf(t);
}

// (yr,yi) = (xr,xi) * W16^tw; tw is compile-time after unrolling -> the
// trivial cases (0: copy, 4: *-i, 2/6: sqrt2/2 forms) fold to add/sub/1-mul,
// which the compiler cannot do itself without fast-math (x*0.0, x-(-0.0)).
__device__ __forceinline__ void twmul(int tw, float xr, float xi,
                                      float& yr, float& yi) {
  if (tw == 0) {
    yr = xr; yi = xi;
  } else if (tw == 4) {
    yr = xi; yi = -xr;
  } else if (tw == 2) {
    yr = 0.70710678118f * (xr + xi);
    yi = 0.70710678118f * (xi - xr);
  } else if (tw == 6) {
    yr = 0.70710678118f * (xi - xr);
    yi = -0.70710678118f * (xr + xi);
  } else {
    yr = xr * W16C[tw] - xi * W16S[tw];
    yi = xr * W16S[tw] + xi * W16C[tw];
  }
}

__global__ __launch_bounds__(256, 8) void dst_fft(const float* __restrict__ X,
                                                  float* __restrict__ Y) {
  // per-wave two-pass transpose buffer: 64 rows x 4 float4 chunks = 4 KB
  __shared__ __align__(16) float lds_all[4][64 * 16];

  const int t = threadIdx.x;
  const int l = t & 63;
  const int w = t >> 6;
  float* lds = &lds_all[w][0];
  const int row = blockIdx.x * 4 + w;           // 0..16383, 1 row per wave

  const int c = l & 3;
  const int m2l = l >> 2;                       // this lane's m2 after transpose
  const int e = ((c & 1) << 1) | (c >> 1);      // brev2(c)
  const int sstar = (int)(__brev((unsigned)m2l) >> 28);  // column with freq m2l
  const int pl = sstar >> 3;                    // which transpose pass feeds us
  const int ccs = (sstar >> 1) & 3;             // local chunk within that pass
  const int subo = (sstar & 1) * 2;             // float offset inside chunk

  const float* xr = X + (size_t)row * 1024;

  // ---- load + even/odd fold (validated layout) ----
  float re[16], im[16], odd[8];
#pragma unroll
  for (int j = 0; j < 8; ++j) {
    float2 v = *(const float2*)(xr + 2 * l + 128 * j);
    re[j] = v.x;
    odd[j] = v.y;
  }
#pragma unroll
  for (int j = 0; j < 8; ++j)
    re[15 - j] = -__shfl_xor(odd[j], 63);

  // ---- phase 1: in-lane DIF-16 over slots ----
  // stage H=8 specialized for real input (im == 0)
#pragma unroll
  for (int o = 0; o < 8; ++o) {
    float d = re[o] - re[o + 8];
    re[o] += re[o + 8];
    im[o] = 0.0f;
    if (o == 0) {
      re[8] = d;            im[8] = 0.0f;
    } else if (o == 4) {
      re[12] = 0.0f;        im[12] = -d;
    } else {
      re[o + 8] = d * W16C[o];
      im[o + 8] = d * W16S[o];
    }
  }
  // stages H=4,2,1 (complex, trivial twiddles specialized; im[0..7]==0
  // const-props through the b=0 half of the H=4 stage)
#pragma unroll
  for (int H = 4; H >= 1; H >>= 1) {
#pragma unroll
    for (int b = 0; b < 16; b += 2 * H) {
#pragma unroll
      for (int o = 0; o < H; ++o) {
        int i0 = b + o, i1 = i0 + H;
        float ar = re[i0] - re[i1], ai = im[i0] - im[i1];
        re[i0] += re[i1];
        im[i0] += im[i1];
        twmul(o * (8 / H), ar, ai, re[i1], im[i1]);
      }
    }
  }

  // twiddle W1024^{l*m2}, computed inline (i=0 is identity)
#pragma unroll
  for (int i = 1; i < 16; ++i) {
    float r = (float)(l * BR4[i]) * (1.0f / 1024.0f);
    float tc = cosr(r), ts = -sinr(r);
    float tr = re[i] * tc - im[i] * ts;
    im[i] = re[i] * ts + im[i] * tc;
    re[i] = tr;
  }

  // ---- two-pass 4KB wave-level LDS transpose (no barrier; per-wave) ----
  // pass p writes global chunks 4p..4p+3 (slots 8p..8p+7); lanes whose
  // needed column lies in that range read all 16 of their values.
  // XOR swizzle on (l>>1)&3: write banks = (row parity) x (4 chunk slots)
  // -> 8 groups x 16B = all 32 banks; reads are 2-way (free).
  float re2[16], im2[16];
#pragma unroll
  for (int p = 0; p < 2; ++p) {
    __asm__ volatile("s_waitcnt lgkmcnt(0)" ::: "memory");  // WAR vs pass-0 reads
#pragma unroll
    for (int cc = 0; cc < 4; ++cc) {
      int ch = 4 * p + cc;
      float4 v = make_float4(re[2 * ch], im[2 * ch],
                             re[2 * ch + 1], im[2 * ch + 1]);
      *(float4*)(lds + l * 16 + ((cc ^ ((l >> 1) & 3)) & 3) * 4) = v;
    }
    __asm__ volatile("s_waitcnt lgkmcnt(0)" ::: "memory");  // RAW: writes done
    if (pl == p) {
#pragma unroll
      for (int i = 0; i < 16; ++i) {
        int r = c + 4 * BR4[i];                 // bit-rev d -> DIT natural out
        int q = (ccs ^ ((r >> 1) & 3)) & 3;
        float2 v = *(const float2*)(lds + r * 16 + q * 4 + subo);
        re2[i] = v.x;
        im2[i] = v.y;
      }
    }
  }

  // ---- in-lane DIT-16 over d -> natural m ----
#pragma unroll
  for (int H = 1; H <= 8; H <<= 1) {
#pragma unroll
    for (int b = 0; b < 16; b += 2 * H) {
#pragma unroll
      for (int o = 0; o < H; ++o) {
        int i0 = b + o, i1 = i0 + H;
        float tr, ti;
        twmul(o * (8 / H), re2[i1], im2[i1], tr, ti);
        re2[i1] = re2[i0] - tr;
        im2[i1] = im2[i0] - ti;
        re2[i0] += tr;
        im2[i0] += ti;
      }
    }
  }

  // ---- twiddle W64^{c*m} (inline; m=0 is identity) ----
#pragma unroll
  for (int m = 1; m < 16; ++m) {
    float r = (float)(c * m) * (1.0f / 64.0f);
    float tc = cosr(r), ts = -sinr(r);
    float tr = re2[m] * tc - im2[m] * ts;
    im2[m] = re2[m] * ts + im2[m] * tc;
    re2[m] = tr;
  }

  // ---- cross-lane DFT_4 over c: DIF radix-2 x2 (quad-perm shuffles) ----
  {
    const float sgA = (c & 2) ? -1.0f : 1.0f;
    const bool rot = (c == 3);                 // *(-i) on high half
    const float sgB = (c & 1) ? -1.0f : 1.0f;
#pragma unroll
    for (int i = 0; i < 16; ++i) {
      float tr = __shfl_xor(re2[i], 2), ti = __shfl_xor(im2[i], 2);
      float ar = tr + sgA * re2[i], ai = ti + sgA * im2[i];
      float br = rot ? ai : ar;
      float bi = rot ? -ar : ai;
      tr = __shfl_xor(br, 1);
      ti = __shfl_xor(bi, 1);
      re2[i] = tr + sgB * br;
      im2[i] = ti + sgB * bi;
    }
  }

  // ---- DCT post-twiddle + store: j = m2 + 16*m + 256*e, Y[1023-j] ----
  float* yr = Y + (size_t)row * 1024 + (1023 - m2l - 256 * e);
#pragma unroll
  for (int s2 = 0; s2 < 16; ++s2) {
    int j = m2l + 16 * s2 + 256 * e;
    float r = (float)j * (1.0f / 4096.0f);     // < 0.25
    yr[-16 * s2] = re2[s2] * cosr(r) + im2[s2] * sinr(r);
  }
}

extern "C" void kernel_launch(void* const* d_in, const int* in_sizes, int n_in,
                              void* d_out, int out_size, void* d_ws, size_t ws_size,
                              hipStream_t stream) {
  const float* X = (const float*)d_in[0];
  float* Y = (float*)d_out;
  // 16384 rows / 1 row per wave / 4 waves per block = 4096 blocks
  dst_fft<<<dim3(4096), dim3(256), 0, stream>>>(X, Y);
}

// Round 2
// 147.137 us; speedup vs baseline: 1.0986x; 1.0986x over previous
//
#include <hip/hip_runtime.h>
#include <cstdint>

// DST-II via FFT, one 1024-point transform per wave, 1 row per wave.
// Y_k = DCT-II(u)_{N-1-k}, u_n = (-1)^n x_n; Makhoul: v_p = x_{2p} (p<512),
// v_p = -x_{2047-2p} (p>=512); V = DFT_1024(v); C_j = Re[e^{-i pi j/2048} V_j];
// Y_k = C_{1023-k}.
//
// DFT_1024, n = l + 64*n2 (l = lane, n2 = slot):
//  phase 1: in-lane DIF-16 over n2 -> slot s holds m2 = brev4(s);
//           twiddle W1024^{l*m2} (computed inline, trans pipe).
//  DFT_64 over l, l = c + 4d (c = l&3):
//   -> two-pass 4KB wave-level LDS transpose (lane' = c + 4*m2 holds all d)
//   -> in-lane DIT-16 over d (bit-rev input via read order, natural m out)
//   -> twiddle W64^{c*m}
//   -> cross-lane DFT_4 over c: shfl_xor(2), shfl_xor(1), output e = brev2(c).
//  k = m2 + 16*m + 256*e; then DCT post-twiddle, store Y[1023-k].
//
// launch_bounds note: live state is ~64 floats (re/im + re2/im2 overlap in
// the two-pass transpose). (256,8) -> 32 VGPRs forced ~170MB/dispatch of
// scratch spill (R1: WRITE_SIZE 240MB, dispatch 82us). (256,6) caps at 85,
// matching natural pressure -> 6 waves/SIMD, no spill.

static constexpr int BR4[16] = {0, 8, 4, 12, 2, 10, 6, 14,
                                1, 9, 5, 13, 3, 11, 7, 15};
// W16^o = e^{-2 pi i o/16}
static constexpr float W16C[8] = {1.0f, 0.9238795325f, 0.7071067812f,
                                  0.3826834324f, 0.0f, -0.3826834324f,
                                  -0.7071067812f, -0.9238795325f};
static constexpr float W16S[8] = {-0.0f, -0.3826834324f, -0.7071067812f,
                                  -0.9238795325f, -1.0f, -0.9238795325f,
                                  -0.7071067812f, -0.3826834324f};

__device__ __forceinline__ float sinr(float r) {   // sin(2*pi*r)
  return __builtin_amdgcn_sinf(r);
}
__device__ __forceinline__ float cosr(float r) {   // cos(2*pi*r), r in [0,1)
  float t = r + 0.25f;
  t -= (t >= 1.0f) ? 1.0f : 0.0f;
  return __builtin_amdgcn_sinf(t);
}

// (yr,yi) = (xr,xi) * W16^tw; tw is compile-time after unrolling -> the
// trivial cases (0: copy, 4: *-i, 2/6: sqrt2/2 forms) fold to add/sub/1-mul,
// which the compiler cannot do itself without fast-math (x*0.0, x-(-0.0)).
__device__ __forceinline__ void twmul(int tw, float xr, float xi,
                                      float& yr, float& yi) {
  if (tw == 0) {
    yr = xr; yi = xi;
  } else if (tw == 4) {
    yr = xi; yi = -xr;
  } else if (tw == 2) {
    yr = 0.70710678118f * (xr + xi);
    yi = 0.70710678118f * (xi - xr);
  } else if (tw == 6) {
    yr = 0.70710678118f * (xi - xr);
    yi = -0.70710678118f * (xr + xi);
  } else {
    yr = xr * W16C[tw] - xi * W16S[tw];
    yi = xr * W16S[tw] + xi * W16C[tw];
  }
}

__global__ __launch_bounds__(256, 6) void dst_fft(const float* __restrict__ X,
                                                  float* __restrict__ Y) {
  // per-wave two-pass transpose buffer: 64 rows x 4 float4 chunks = 4 KB
  __shared__ __align__(16) float lds_all[4][64 * 16];

  const int t = threadIdx.x;
  const int l = t & 63;
  const int w = t >> 6;
  float* lds = &lds_all[w][0];
  const int row = blockIdx.x * 4 + w;           // 0..16383, 1 row per wave

  const int c = l & 3;
  const int m2l = l >> 2;                       // this lane's m2 after transpose
  const int e = ((c & 1) << 1) | (c >> 1);      // brev2(c)
  const int sstar = (int)(__brev((unsigned)m2l) >> 28);  // column with freq m2l
  const int pl = sstar >> 3;                    // which transpose pass feeds us
  const int ccs = (sstar >> 1) & 3;             // local chunk within that pass
  const int subo = (sstar & 1) * 2;             // float offset inside chunk

  const float* xr = X + (size_t)row * 1024;

  // ---- load + even/odd fold (validated layout) ----
  float re[16], im[16], odd[8];
#pragma unroll
  for (int j = 0; j < 8; ++j) {
    float2 v = *(const float2*)(xr + 2 * l + 128 * j);
    re[j] = v.x;
    odd[j] = v.y;
  }
#pragma unroll
  for (int j = 0; j < 8; ++j)
    re[15 - j] = -__shfl_xor(odd[j], 63);

  // ---- phase 1: in-lane DIF-16 over slots ----
  // stage H=8 specialized for real input (im == 0)
#pragma unroll
  for (int o = 0; o < 8; ++o) {
    float d = re[o] - re[o + 8];
    re[o] += re[o + 8];
    im[o] = 0.0f;
    if (o == 0) {
      re[8] = d;            im[8] = 0.0f;
    } else if (o == 4) {
      re[12] = 0.0f;        im[12] = -d;
    } else {
      re[o + 8] = d * W16C[o];
      im[o + 8] = d * W16S[o];
    }
  }
  // stages H=4,2,1 (complex, trivial twiddles specialized; im[0..7]==0
  // const-props through the b=0 half of the H=4 stage)
#pragma unroll
  for (int H = 4; H >= 1; H >>= 1) {
#pragma unroll
    for (int b = 0; b < 16; b += 2 * H) {
#pragma unroll
      for (int o = 0; o < H; ++o) {
        int i0 = b + o, i1 = i0 + H;
        float ar = re[i0] - re[i1], ai = im[i0] - im[i1];
        re[i0] += re[i1];
        im[i0] += im[i1];
        twmul(o * (8 / H), ar, ai, re[i1], im[i1]);
      }
    }
  }

  // twiddle W1024^{l*m2}, computed inline (i=0 is identity)
#pragma unroll
  for (int i = 1; i < 16; ++i) {
    float r = (float)(l * BR4[i]) * (1.0f / 1024.0f);
    float tc = cosr(r), ts = -sinr(r);
    float tr = re[i] * tc - im[i] * ts;
    im[i] = re[i] * ts + im[i] * tc;
    re[i] = tr;
  }

  // ---- two-pass 4KB wave-level LDS transpose (no barrier; per-wave) ----
  // pass p writes global chunks 4p..4p+3 (slots 8p..8p+7); lanes whose
  // needed column lies in that range read all 16 of their values.
  // XOR swizzle on (l>>1)&3: write banks = (row parity) x (4 chunk slots)
  // -> 8 groups x 16B = all 32 banks; reads are 2-way (free).
  float re2[16], im2[16];
#pragma unroll
  for (int p = 0; p < 2; ++p) {
    __asm__ volatile("s_waitcnt lgkmcnt(0)" ::: "memory");  // WAR vs pass-0 reads
#pragma unroll
    for (int cc = 0; cc < 4; ++cc) {
      int ch = 4 * p + cc;
      float4 v = make_float4(re[2 * ch], im[2 * ch],
                             re[2 * ch + 1], im[2 * ch + 1]);
      *(float4*)(lds + l * 16 + ((cc ^ ((l >> 1) & 3)) & 3) * 4) = v;
    }
    __asm__ volatile("s_waitcnt lgkmcnt(0)" ::: "memory");  // RAW: writes done
    if (pl == p) {
#pragma unroll
      for (int i = 0; i < 16; ++i) {
        int r = c + 4 * BR4[i];                 // bit-rev d -> DIT natural out
        int q = (ccs ^ ((r >> 1) & 3)) & 3;
        float2 v = *(const float2*)(lds + r * 16 + q * 4 + subo);
        re2[i] = v.x;
        im2[i] = v.y;
      }
    }
  }

  // ---- in-lane DIT-16 over d -> natural m ----
#pragma unroll
  for (int H = 1; H <= 8; H <<= 1) {
#pragma unroll
    for (int b = 0; b < 16; b += 2 * H) {
#pragma unroll
      for (int o = 0; o < H; ++o) {
        int i0 = b + o, i1 = i0 + H;
        float tr, ti;
        twmul(o * (8 / H), re2[i1], im2[i1], tr, ti);
        re2[i1] = re2[i0] - tr;
        im2[i1] = im2[i0] - ti;
        re2[i0] += tr;
        im2[i0] += ti;
      }
    }
  }

  // ---- twiddle W64^{c*m} (inline; m=0 is identity) ----
#pragma unroll
  for (int m = 1; m < 16; ++m) {
    float r = (float)(c * m) * (1.0f / 64.0f);
    float tc = cosr(r), ts = -sinr(r);
    float tr = re2[m] * tc - im2[m] * ts;
    im2[m] = re2[m] * ts + im2[m] * tc;
    re2[m] = tr;
  }

  // ---- cross-lane DFT_4 over c: DIF radix-2 x2 (quad-perm shuffles) ----
  {
    const float sgA = (c & 2) ? -1.0f : 1.0f;
    const bool rot = (c == 3);                 // *(-i) on high half
    const float sgB = (c & 1) ? -1.0f : 1.0f;
#pragma unroll
    for (int i = 0; i < 16; ++i) {
      float tr = __shfl_xor(re2[i], 2), ti = __shfl_xor(im2[i], 2);
      float ar = tr + sgA * re2[i], ai = ti + sgA * im2[i];
      float br = rot ? ai : ar;
      float bi = rot ? -ar : ai;
      tr = __shfl_xor(br, 1);
      ti = __shfl_xor(bi, 1);
      re2[i] = tr + sgB * br;
      im2[i] = ti + sgB * bi;
    }
  }

  // ---- DCT post-twiddle + store: j = m2 + 16*m + 256*e, Y[1023-j] ----
  float* yr = Y + (size_t)row * 1024 + (1023 - m2l - 256 * e);
#pragma unroll
  for (int s2 = 0; s2 < 16; ++s2) {
    int j = m2l + 16 * s2 + 256 * e;
    float r = (float)j * (1.0f / 4096.0f);     // < 0.25
    yr[-16 * s2] = re2[s2] * cosr(r) + im2[s2] * sinr(r);
  }
}

extern "C" void kernel_launch(void* const* d_in, const int* in_sizes, int n_in,
                              void* d_out, int out_size, void* d_ws, size_t ws_size,
                              hipStream_t stream) {
  const float* X = (const float*)d_in[0];
  float* Y = (float*)d_out;
  // 16384 rows / 1 row per wave / 4 waves per block = 4096 blocks
  dst_fft<<<dim3(4096), dim3(256), 0, stream>>>(X, Y);
}

// Round 3
// 118.507 us; speedup vs baseline: 1.3641x; 1.2416x over previous
//
#include <hip/hip_runtime.h>
#include <cstdint>

// DST-II via FFT, one 1024-point transform per wave, 1 row per wave.
// Y_k = DCT-II(u)_{N-1-k}, u_n = (-1)^n x_n; Makhoul: v_p = x_{2p} (p<512),
// v_p = -x_{2047-2p} (p>=512); V = DFT_1024(v); C_j = Re[e^{-i pi j/2048} V_j];
// Y_k = C_{1023-k}.
//
// DFT_1024, n = l + 64*n2 (l = lane, n2 = slot):
//  phase 1: in-lane DIF-16 over n2 -> slot s holds m2 = brev4(s);
//           twiddle W1024^{l*m2} via power-ladder off one base sin/cos pair.
//  DFT_64 over l, l = c + 4d (c = l&3):
//   -> two-pass 4KB wave-level LDS transpose (lane' = c + 4*m2 holds all d)
//   -> in-lane DIT-16 over d (bit-rev input via read order, natural m out)
//   -> twiddle W64^{c*m} via ladder off base e^{-2pi i c/64}
//   -> cross-lane DFT_4 over c: shfl_xor(2), shfl_xor(1), output e = brev2(c).
//  k = m2 + 16*m + 256*e; DCT post-twiddle via constant-step rotation
//  (delta = 2pi/256), store Y[1023-k].
//
// launch_bounds note (R1/R2 empirics): second arg N caps VGPR at ~512/(2N):
// (256,8)->32 VGPR, (256,6)->40 VGPR -- both spilled ~120-170MB/dispatch
// (WRITE_SIZE 240/185MB vs ideal 64MB). Live state is ~64-80 floats, so
// (256,3) -> cap ~85 fits spill-free while guaranteeing 6 waves/SIMD.
//
// Transcendental budget: 6 v_sin per row-lane (was 92). The three twiddle
// families are unit-magnitude fp32 rotation ladders; drift over <=15 complex
// muls ~1e-6, irrelevant at absmax tolerance 0.5.

static constexpr int BR4[16] = {0, 8, 4, 12, 2, 10, 6, 14,
                                1, 9, 5, 13, 3, 11, 7, 15};
// W16^o = e^{-2 pi i o/16}
static constexpr float W16C[8] = {1.0f, 0.9238795325f, 0.7071067812f,
                                  0.3826834324f, 0.0f, -0.3826834324f,
                                  -0.7071067812f, -0.9238795325f};
static constexpr float W16S[8] = {-0.0f, -0.3826834324f, -0.7071067812f,
                                  -0.9238795325f, -1.0f, -0.9238795325f,
                                  -0.7071067812f, -0.3826834324f};

__device__ __forceinline__ float sinr(float r) {   // sin(2*pi*r)
  return __builtin_amdgcn_sinf(r);
}
__device__ __forceinline__ float cosr(float r) {   // cos(2*pi*r), r in [0,1)
  float t = r + 0.25f;
  t -= (t >= 1.0f) ? 1.0f : 0.0f;
  return __builtin_amdgcn_sinf(t);
}

// (yr,yi) = (xr,xi) * W16^tw; tw is compile-time after unrolling -> the
// trivial cases (0: copy, 4: *-i, 2/6: sqrt2/2 forms) fold to add/sub/1-mul,
// which the compiler cannot do itself without fast-math (x*0.0, x-(-0.0)).
__device__ __forceinline__ void twmul(int tw, float xr, float xi,
                                      float& yr, float& yi) {
  if (tw == 0) {
    yr = xr; yi = xi;
  } else if (tw == 4) {
    yr = xi; yi = -xr;
  } else if (tw == 2) {
    yr = 0.70710678118f * (xr + xi);
    yi = 0.70710678118f * (xi - xr);
  } else if (tw == 6) {
    yr = 0.70710678118f * (xi - xr);
    yi = -0.70710678118f * (xr + xi);
  } else {
    yr = xr * W16C[tw] - xi * W16S[tw];
    yi = xr * W16S[tw] + xi * W16C[tw];
  }
}

__global__ __launch_bounds__(256, 3) void dst_fft(const float* __restrict__ X,
                                                  float* __restrict__ Y) {
  // per-wave two-pass transpose buffer: 64 rows x 4 float4 chunks = 4 KB
  __shared__ __align__(16) float lds_all[4][64 * 16];

  const int t = threadIdx.x;
  const int l = t & 63;
  const int w = t >> 6;
  float* lds = &lds_all[w][0];
  const int row = blockIdx.x * 4 + w;           // 0..16383, 1 row per wave

  const int c = l & 3;
  const int m2l = l >> 2;                       // this lane's m2 after transpose
  const int e = ((c & 1) << 1) | (c >> 1);      // brev2(c)
  const int sstar = (int)(__brev((unsigned)m2l) >> 28);  // column with freq m2l
  const int pl = sstar >> 3;                    // which transpose pass feeds us
  const int ccs = (sstar >> 1) & 3;             // local chunk within that pass
  const int subo = (sstar & 1) * 2;             // float offset inside chunk

  const float* xr = X + (size_t)row * 1024;

  // ---- load + even/odd fold (validated layout) ----
  float re[16], im[16], odd[8];
#pragma unroll
  for (int j = 0; j < 8; ++j) {
    float2 v = *(const float2*)(xr + 2 * l + 128 * j);
    re[j] = v.x;
    odd[j] = v.y;
  }
#pragma unroll
  for (int j = 0; j < 8; ++j)
    re[15 - j] = -__shfl_xor(odd[j], 63);

  // ---- phase 1: in-lane DIF-16 over slots ----
  // stage H=8 specialized for real input (im == 0)
#pragma unroll
  for (int o = 0; o < 8; ++o) {
    float d = re[o] - re[o + 8];
    re[o] += re[o + 8];
    im[o] = 0.0f;
    if (o == 0) {
      re[8] = d;            im[8] = 0.0f;
    } else if (o == 4) {
      re[12] = 0.0f;        im[12] = -d;
    } else {
      re[o + 8] = d * W16C[o];
      im[o + 8] = d * W16S[o];
    }
  }
  // stages H=4,2,1 (complex, trivial twiddles specialized; im[0..7]==0
  // const-props through the b=0 half of the H=4 stage)
#pragma unroll
  for (int H = 4; H >= 1; H >>= 1) {
#pragma unroll
    for (int b = 0; b < 16; b += 2 * H) {
#pragma unroll
      for (int o = 0; o < H; ++o) {
        int i0 = b + o, i1 = i0 + H;
        float ar = re[i0] - re[i1], ai = im[i0] - im[i1];
        re[i0] += re[i1];
        im[i0] += im[i1];
        twmul(o * (8 / H), ar, ai, re[i1], im[i1]);
      }
    }
  }

  // ---- twiddle W1024^{l*m2}: power ladder off base w = e^{-2pi i l/1024} ----
  // w^m2 is applied at index BR4[m2] (BR4 is an involution); 2 sins + 14 cmuls
  {
    float rb = (float)l * (1.0f / 1024.0f);
    float wr = cosr(rb), wi = -sinr(rb);
    float cr = wr, ci = wi;
#pragma unroll
    for (int m2 = 1; m2 < 16; ++m2) {
      if (m2 > 1) {                       // advance ladder: c *= w
        float nr = cr * wr - ci * wi;
        ci = cr * wi + ci * wr;
        cr = nr;
      }
      int i = BR4[m2];
      float tr = re[i] * cr - im[i] * ci;
      im[i] = re[i] * ci + im[i] * cr;
      re[i] = tr;
    }
  }

  // ---- two-pass 4KB wave-level LDS transpose (no barrier; per-wave) ----
  // pass p writes global chunks 4p..4p+3 (slots 8p..8p+7); lanes whose
  // needed column lies in that range read all 16 of their values.
  // XOR swizzle on (l>>1)&3: write banks = (row parity) x (4 chunk slots)
  // -> 8 groups x 16B = all 32 banks; reads are 2-way (free).
  float re2[16], im2[16];
#pragma unroll
  for (int p = 0; p < 2; ++p) {
    if (p)  // WAR: pass-0 reads must drain before overwriting the buffer
      __asm__ volatile("s_waitcnt lgkmcnt(0)" ::: "memory");
#pragma unroll
    for (int cc = 0; cc < 4; ++cc) {
      int ch = 4 * p + cc;
      float4 v = make_float4(re[2 * ch], im[2 * ch],
                             re[2 * ch + 1], im[2 * ch + 1]);
      *(float4*)(lds + l * 16 + ((cc ^ ((l >> 1) & 3)) & 3) * 4) = v;
    }
    __asm__ volatile("s_waitcnt lgkmcnt(0)" ::: "memory");  // RAW: writes done
    if (pl == p) {
#pragma unroll
      for (int i = 0; i < 16; ++i) {
        int r = c + 4 * BR4[i];                 // bit-rev d -> DIT natural out
        int q = (ccs ^ ((r >> 1) & 3)) & 3;
        float2 v = *(const float2*)(lds + r * 16 + q * 4 + subo);
        re2[i] = v.x;
        im2[i] = v.y;
      }
    }
  }

  // ---- in-lane DIT-16 over d -> natural m ----
#pragma unroll
  for (int H = 1; H <= 8; H <<= 1) {
#pragma unroll
    for (int b = 0; b < 16; b += 2 * H) {
#pragma unroll
      for (int o = 0; o < H; ++o) {
        int i0 = b + o, i1 = i0 + H;
        float tr, ti;
        twmul(o * (8 / H), re2[i1], im2[i1], tr, ti);
        re2[i1] = re2[i0] - tr;
        im2[i1] = im2[i0] - ti;
        re2[i0] += tr;
        im2[i0] += ti;
      }
    }
  }

  // ---- twiddle W64^{c*m}: ladder off base b = e^{-2pi i c/64} ----
  // 2 sins + 14 cmuls (c=0 lanes run the same uniform code with b=1)
  {
    float rb = (float)c * (1.0f / 64.0f);
    float br = cosr(rb), bi = -sinr(rb);
    float cr = br, ci = bi;
#pragma unroll
    for (int m = 1; m < 16; ++m) {
      if (m > 1) {                        // advance ladder: c *= b
        float nr = cr * br - ci * bi;
        ci = cr * bi + ci * br;
        cr = nr;
      }
      float tr = re2[m] * cr - im2[m] * ci;
      im2[m] = re2[m] * ci + im2[m] * cr;
      re2[m] = tr;
    }
  }

  // ---- cross-lane DFT_4 over c: DIF radix-2 x2 (quad-perm shuffles) ----
  {
    const float sgA = (c & 2) ? -1.0f : 1.0f;
    const bool rot = (c == 3);                 // *(-i) on high half
    const float sgB = (c & 1) ? -1.0f : 1.0f;
#pragma unroll
    for (int i = 0; i < 16; ++i) {
      float tr = __shfl_xor(re2[i], 2), ti = __shfl_xor(im2[i], 2);
      float ar = tr + sgA * re2[i], ai = ti + sgA * im2[i];
      float br = rot ? ai : ar;
      float bi = rot ? -ar : ai;
      tr = __shfl_xor(br, 1);
      ti = __shfl_xor(bi, 1);
      re2[i] = tr + sgB * br;
      im2[i] = ti + sgB * bi;
    }
  }

  // ---- DCT post-twiddle + store: j = m2 + 16*m + 256*e, Y[1023-j] ----
  // phase steps by a constant 2pi/256 per s2 -> rotation recurrence,
  // 2 sins + 15 rotations (4 ops each) instead of 32 sins.
  {
    const float DC = 0.99969881869620422f;   // cos(2*pi/256)
    const float DS = 0.02454122852291229f;   // sin(2*pi/256)
    float r0 = (float)(m2l + 256 * e) * (1.0f / 4096.0f);   // < 0.1912
    float pc = cosr(r0), ps = sinr(r0);
    float* yr = Y + (size_t)row * 1024 + (1023 - m2l - 256 * e);
#pragma unroll
    for (int s2 = 0; s2 < 16; ++s2) {
      yr[-16 * s2] = re2[s2] * pc + im2[s2] * ps;
      if (s2 < 15) {
        float nc = pc * DC - ps * DS;
        ps = ps * DC + pc * DS;
        pc = nc;
      }
    }
  }
}

extern "C" void kernel_launch(void* const* d_in, const int* in_sizes, int n_in,
                              void* d_out, int out_size, void* d_ws, size_t ws_size,
                              hipStream_t stream) {
  const float* X = (const float*)d_in[0];
  float* Y = (float*)d_out;
  // 16384 rows / 1 row per wave / 4 waves per block = 4096 blocks
  dst_fft<<<dim3(4096), dim3(256), 0, stream>>>(X, Y);
}